// Round 10
// baseline (440.621 us; speedup 1.0000x reference)
//
#include <hip/hip_runtime.h>
#include <hip/hip_bf16.h>
#include <cmath>

using bf16 = __hip_bfloat16;
typedef __attribute__((ext_vector_type(8))) short short8;
typedef __attribute__((ext_vector_type(4))) short s16x4;
typedef __attribute__((ext_vector_type(4))) float f32x4;

#define B_   4
#define S_   2048
#define H_   768
#define H2_  1536
#define H3_  2304
#define NH_  8
#define DH_  96
#define L_   128
#define ML_  15
#define LG_  8
#define QR_  128
#define CH_  32
#define NS_  2       // NS_=4 measured WORSE (R8)
#define SLC_ (S_ / NS_)
#define ELD  36      // Es row stride (shorts): 18dw, clean
#define VTLD 40      // Vt row stride: 20dw, 2-way free
#define KLD  104     // Ks/Qs row stride: 52dw, 2-way free
#define VTR  112     // 96 d + 16 ones-rows (denominator trick)
#define ALD  40      // 64-tile gemm stride: 20dw (32 was 8..16-way)
#define ALQ  72      // 128-tile gemm stride for BK=64: 36dw, uniform banks

__device__ __forceinline__ float gelu_exact(float v) {
    return 0.5f * v * (1.0f + erff(v * 0.7071067811865475f));
}
__device__ __forceinline__ short f2bs(float f) {
    bf16 h = __float2bfloat16(f);
    return *reinterpret_cast<short*>(&h);
}
__device__ __forceinline__ short8 ld_frag8(const short* p) {
    union { short8 v; s16x4 h[2]; } u;
    u.h[0] = *(const s16x4*)p;
    u.h[1] = *(const s16x4*)(p + 4);
    return u.v;
}

// fp32 -> bf16 bulk convert of hidden (n1) and in_proj_w (n2), one launch
__global__ __launch_bounds__(256) void f2b2_k(
    const float* __restrict__ s1, bf16* __restrict__ d1, int n1,
    const float* __restrict__ s2, bf16* __restrict__ d2, int n2)
{
    const int i = (blockIdx.x * 256 + threadIdx.x) * 8;
    const float* src; bf16* dst; int off;
    if (i < n1) { src = s1; dst = d1; off = i; }
    else if (i < n1 + n2) { src = s2; dst = d2; off = i - n1; }
    else return;
    float4 a = *(const float4*)(src + off);
    float4 b = *(const float4*)(src + off + 4);
    short8 r;
    r[0] = f2bs(a.x); r[1] = f2bs(a.y); r[2] = f2bs(a.z); r[3] = f2bs(a.w);
    r[4] = f2bs(b.x); r[5] = f2bs(b.y); r[6] = f2bs(b.z); r[7] = f2bs(b.w);
    *(short8*)(dst + off) = r;
}

// register pack for 8 elements of bf16/fp32 (prefetch staging)
template <typename T> struct Pk8;
template <> struct Pk8<bf16>  { int4 v; };
template <> struct Pk8<float> { float4 a, b; };
template <typename T> __device__ __forceinline__ Pk8<T> ld8(const T* p);
template <> __device__ __forceinline__ Pk8<bf16> ld8(const bf16* p) {
    Pk8<bf16> r; r.v = *(const int4*)p; return r;
}
template <> __device__ __forceinline__ Pk8<float> ld8(const float* p) {
    Pk8<float> r; r.a = *(const float4*)p; r.b = *(const float4*)(p + 4); return r;
}
template <typename T> __device__ __forceinline__ void st8(const Pk8<T>& v, bf16* dst);
template <> __device__ __forceinline__ void st8<bf16>(const Pk8<bf16>& v, bf16* dst) {
    *(int4*)dst = v.v;
}
template <> __device__ __forceinline__ void st8<float>(const Pk8<float>& v, bf16* dst) {
    short8 r;
    r[0] = f2bs(v.a.x); r[1] = f2bs(v.a.y); r[2] = f2bs(v.a.z); r[3] = f2bs(v.a.w);
    r[4] = f2bs(v.b.x); r[5] = f2bs(v.b.y); r[6] = f2bs(v.b.z); r[7] = f2bs(v.b.w);
    *(short8*)dst = r;
}

// ---------------------------------------------------------------------------
// 128x128-tile qkv GEMM, BK=64 (half the barriers of BK=32), register
// prefetch, LDS stride ALQ=72 (uniform banks for b128 read+write).
// Q/K cols -> qk row-major [B*S,1536]; V cols -> vt transposed [b,h,d,s].
// ---------------------------------------------------------------------------
__global__ __launch_bounds__(256) void gemm128_qkv(
    const bf16* __restrict__ A, const bf16* __restrict__ Bm,
    const float* __restrict__ bias, bf16* __restrict__ qk,
    bf16* __restrict__ vt, int M, int K)
{
    __shared__ alignas(16) bf16 As[128 * ALQ];
    __shared__ alignas(16) bf16 Bs[128 * ALQ];
    const int t = threadIdx.x;
    const int wave = t >> 6, lane = t & 63;
    const int l15 = lane & 15, quad = lane >> 4;
    const int m0 = blockIdx.x * 128, n0 = blockIdx.y * 128;
    const int wm = wave & 1, wn = wave >> 1;
    const int srow = t >> 1, scol = (t & 1) * 32;   // each thread: 64B of one row

    const bf16* aP = A + (size_t)(m0 + srow) * K + scol;
    const bf16* bP = Bm + (size_t)(n0 + srow) * K + scol;
    bf16* aL = &As[srow * ALQ + scol];
    bf16* bL = &Bs[srow * ALQ + scol];

    f32x4 acc[4][4];
#pragma unroll
    for (int i = 0; i < 4; i++)
#pragma unroll
        for (int j = 0; j < 4; j++) acc[i][j] = (f32x4){0.f, 0.f, 0.f, 0.f};

    int4 ra[4], rb[4];
#pragma unroll
    for (int c = 0; c < 4; c++) {
        ra[c] = *(const int4*)(aP + c * 8);
        rb[c] = *(const int4*)(bP + c * 8);
    }

    for (int k0 = 0; k0 < K; k0 += 64) {
        __syncthreads();
#pragma unroll
        for (int c = 0; c < 4; c++) {
            *(int4*)(aL + c * 8) = ra[c];
            *(int4*)(bL + c * 8) = rb[c];
        }
        __syncthreads();
        if (k0 + 64 < K) {
#pragma unroll
            for (int c = 0; c < 4; c++) {
                ra[c] = *(const int4*)(aP + k0 + 64 + c * 8);
                rb[c] = *(const int4*)(bP + k0 + 64 + c * 8);
            }
        }
#pragma unroll
        for (int kf = 0; kf < 2; kf++) {
            short8 af[4], bfq[4];
#pragma unroll
            for (int i = 0; i < 4; i++)
                af[i] = *(const short8*)&As[(wm * 64 + i * 16 + l15) * ALQ + kf * 32 + quad * 8];
#pragma unroll
            for (int j = 0; j < 4; j++)
                bfq[j] = *(const short8*)&Bs[(wn * 64 + j * 16 + l15) * ALQ + kf * 32 + quad * 8];
#pragma unroll
            for (int i = 0; i < 4; i++)
#pragma unroll
                for (int j = 0; j < 4; j++)
                    acc[i][j] = __builtin_amdgcn_mfma_f32_16x16x32_bf16(af[i], bfq[j], acc[i][j], 0, 0, 0);
        }
    }

    if (n0 < H2_) {
#pragma unroll
        for (int j = 0; j < 4; j++) {
            const int col = n0 + wn * 64 + j * 16 + l15;
            const float bv = bias[col];
#pragma unroll
            for (int i = 0; i < 4; i++) {
                const int row = m0 + wm * 64 + i * 16 + quad * 4;
#pragma unroll
                for (int r = 0; r < 4; r++)
                    qk[(size_t)(row + r) * H2_ + col] = __float2bfloat16(acc[i][j][r] + bv);
            }
        }
    } else {
#pragma unroll
        for (int j = 0; j < 4; j++) {
            const int col = n0 + wn * 64 + j * 16 + l15;
            const float bv = bias[col];
            const int dfull = col - H2_;
            const int hh = dfull / DH_, d = dfull - hh * DH_;
#pragma unroll
            for (int i = 0; i < 4; i++) {
                const int row = m0 + wm * 64 + i * 16 + quad * 4;
                const int b = row >> 11, s = row & (S_ - 1);
                s16x4 pk;
#pragma unroll
                for (int r = 0; r < 4; r++) pk[r] = f2bs(acc[i][j][r] + bv);
                *(s16x4*)&vt[((size_t)(b * NH_ + hh) * DH_ + d) * S_ + s] = pk;
            }
        }
    }
}

// ---------------------------------------------------------------------------
// 64x64-tile GEMM with register prefetch (loads for k+1 issued during k's
// compute — the old version exposed ~600cyc global latency every iteration
// on a 96-block grid that cannot hide it). LDS stride ALD=40.
// ---------------------------------------------------------------------------
template <typename TA, typename TB, bool OUT_BF16>
__global__ __launch_bounds__(256) void gemm_bt(
    const TA* __restrict__ A, const TB* __restrict__ Bm,
    const float* __restrict__ bias, void* __restrict__ Cout,
    int M, int N, int K, int ldc, int coff)
{
    __shared__ alignas(16) bf16 As[64 * ALD];
    __shared__ alignas(16) bf16 Bs[64 * ALD];
    const int t = threadIdx.x;
    const int wave = t >> 6, lane = t & 63;
    const int l15 = lane & 15, quad = lane >> 4;
    const int m0 = blockIdx.x * 64, n0 = blockIdx.y * 64;
    const int srow = t >> 2, schk = (t & 3) * 8;

    const TA* aPtr = A + (size_t)(m0 + srow) * K + schk;
    const TB* bPtr = Bm + (size_t)(n0 + srow) * K + schk;
    bf16* aL = &As[srow * ALD + schk];
    bf16* bL = &Bs[srow * ALD + schk];

    f32x4 acc[4] = {{0.f,0.f,0.f,0.f},{0.f,0.f,0.f,0.f},
                    {0.f,0.f,0.f,0.f},{0.f,0.f,0.f,0.f}};
    const int aoff = (wave * 16 + l15) * ALD + quad * 8;

    Pk8<TA> pa = ld8<TA>(aPtr);
    Pk8<TB> pb = ld8<TB>(bPtr);

    for (int k0 = 0; k0 < K; k0 += 32) {
        __syncthreads();
        st8<TA>(pa, aL);
        st8<TB>(pb, bL);
        __syncthreads();
        if (k0 + 32 < K) {
            pa = ld8<TA>(aPtr + k0 + 32);
            pb = ld8<TB>(bPtr + k0 + 32);
        }
        short8 af = *(const short8*)&As[aoff];
#pragma unroll
        for (int nt = 0; nt < 4; nt++) {
            short8 bfr = *(const short8*)&Bs[(nt * 16 + l15) * ALD + quad * 8];
            acc[nt] = __builtin_amdgcn_mfma_f32_16x16x32_bf16(af, bfr, acc[nt], 0, 0, 0);
        }
    }

#pragma unroll
    for (int nt = 0; nt < 4; nt++) {
        int col = n0 + nt * 16 + l15;
        float bv = bias[col];
#pragma unroll
        for (int r = 0; r < 4; r++) {
            int row = m0 + wave * 16 + quad * 4 + r;
            float v = acc[nt][r] + bv;
            if (OUT_BF16) ((bf16*)Cout)[(size_t)row * ldc + coff + col] = __float2bfloat16(v);
            else          ((float*)Cout)[(size_t)row * ldc + coff + col] = v;
        }
    }
}

// ---------------------------------------------------------------------------
// Attention slice (R7-proven core) + hoisted ones-rows (rewritten only when
// the ctx mask pattern changes) + ctx-uniform exp fast path.
// ---------------------------------------------------------------------------
__global__ __launch_bounds__(256) void attn_slice(
    const bf16* __restrict__ qk, const bf16* __restrict__ vtg,
    const int* __restrict__ line_starts, const int* __restrict__ line_lens,
    const int* __restrict__ context_len,
    bf16* __restrict__ Opart, float* __restrict__ Dpart)
{
    __shared__ alignas(16) union {
        short Qs[QR_ * KLD];                       // 26624 B (staging phase)
        struct {
            short Ks[CH_ * KLD];                   //  6656 B
            short Vt[VTR * VTLD];                  //  8960 B
            short Es[QR_ * ELD];                   //  9216 B
        } s;                                       // 24832 B
    } U;

    const int t = threadIdx.x;
    const int idx = blockIdx.x;          // (b*8+h)*16 + lg
    const int slice = blockIdx.y;
    const int lg = idx & 15;
    const int bh = idx >> 4;
    const int h = bh & 7, b = bh >> 3;
    const int ctx = context_len[b];
    const int wave = t >> 6, lane = t & 63;
    const int l15 = lane & 15, quad = lane >> 4;

    // ---- stage Q: 128 rows x 96 bf16 (pad/invalid rows -> 0), stride KLD
    for (int ii = t; ii < QR_ * 12; ii += 256) {
        const int r = ii / 12, ck = ii - r * 12;
        int4 val; val.x = val.y = val.z = val.w = 0;
        if (r < LG_ * ML_) {
            const int li = r / ML_, m = r - li * ML_;
            const int line = lg * LG_ + li;
            const int len = line_lens[b * L_ + line];
            if (m < len) {
                int sPos = line_starts[b * L_ + line] + m;
                sPos = min(max(sPos, 0), S_ - 1);
                val = *(const int4*)(qk + (size_t)(b * S_ + sPos) * H2_ + h * DH_ + ck * 8);
            }
        }
        *(int4*)&U.Qs[r * KLD + ck * 8] = val;
    }
    __syncthreads();

    short8 qf[2][3];
#pragma unroll
    for (int st = 0; st < 2; st++)
#pragma unroll
        for (int kf = 0; kf < 3; kf++)
            qf[st][kf] = *(const short8*)(U.Qs + ((wave + 4 * st) * 16 + l15) * KLD + kf * 32 + quad * 8);
    __syncthreads();   // Qs fully consumed -> union area reusable

    f32x4 Oacc[2][7];
#pragma unroll
    for (int st = 0; st < 2; st++)
#pragma unroll
        for (int nt = 0; nt < 7; nt++) Oacc[st][nt] = (f32x4){0.f, 0.f, 0.f, 0.f};

    const float scale = 0.10206207261596577f;  // 1/sqrt(96)
    const size_t kbase = (size_t)b * S_ * H2_ + H_ + h * DH_;
    const size_t vbase = (size_t)(b * NH_ + h) * DH_ * S_;
    const int cbase = slice * SLC_;

    const int k0r = t / 12,        k0c = t - k0r * 12;
    const int k1r = (256 + t) / 12, k1c = (256 + t) - k1r * 12;
    const int v0d = t >> 2,        v0s = (t & 3) * 8;
    const int v1d = (256 + t) >> 2, v1s = ((256 + t) & 3) * 8;
    const int on_r = t >> 4, on_c = t & 15;

    int4 rk0, rk1, rv0, rv1;
    {
        rk0 = *(const int4*)(qk + kbase + (size_t)(cbase + k0r) * H2_ + k0c * 8);
        rv0 = *(const int4*)(vtg + vbase + (size_t)v0d * S_ + cbase + v0s);
        if (t < 128) {
            rk1 = *(const int4*)(qk + kbase + (size_t)(cbase + k1r) * H2_ + k1c * 8);
            rv1 = *(const int4*)(vtg + vbase + (size_t)v1d * S_ + cbase + v1s);
        }
    }

    int ones_state = -1;   // -1 unwritten, 0 all-zero, 1 all-one, 2 mixed

    for (int ci = 0; ci < SLC_ / CH_; ci++) {
        const int c0 = cbase + ci * CH_;
        __syncthreads();
        *(int4*)&U.s.Ks[k0r * KLD + k0c * 8] = rk0;
        *(int4*)&U.s.Vt[v0d * VTLD + v0s] = rv0;
        if (t < 128) {
            *(int4*)&U.s.Ks[k1r * KLD + k1c * 8] = rk1;
            *(int4*)&U.s.Vt[v1d * VTLD + v1s] = rv1;
        }
        {   // ones-rows 96..111: rewrite only when mask pattern changes
            const int st_now = (c0 + CH_ <= ctx) ? 1 : ((c0 >= ctx) ? 0 : 2);
            if (st_now != ones_state || st_now == 2) {
                unsigned int lo = (c0 + 2 * on_c)     < ctx ? 0x3f80u : 0u;
                unsigned int hi = (c0 + 2 * on_c + 1) < ctx ? 0x3f80u : 0u;
                ((unsigned int*)&U.s.Vt[(96 + on_r) * VTLD])[on_c] = lo | (hi << 16);
                ones_state = st_now;
            }
        }
        __syncthreads();

        if (ci + 1 < SLC_ / CH_) {
            const int cn = c0 + CH_;
            rk0 = *(const int4*)(qk + kbase + (size_t)(cn + k0r) * H2_ + k0c * 8);
            rv0 = *(const int4*)(vtg + vbase + (size_t)v0d * S_ + cn + v0s);
            if (t < 128) {
                rk1 = *(const int4*)(qk + kbase + (size_t)(cn + k1r) * H2_ + k1c * 8);
                rv1 = *(const int4*)(vtg + vbase + (size_t)v1d * S_ + cn + v1s);
            }
        }

        // ---- S^T = K*Q^T via MFMA (A=K rows s, B=Q cols q)
        f32x4 acc[2][2] = {{{0.f,0.f,0.f,0.f},{0.f,0.f,0.f,0.f}},
                           {{0.f,0.f,0.f,0.f},{0.f,0.f,0.f,0.f}}};
#pragma unroll
        for (int ns = 0; ns < 2; ns++)
#pragma unroll
            for (int kf = 0; kf < 3; kf++) {
                short8 kfr = *(const short8*)(U.s.Ks + (ns * 16 + l15) * KLD + kf * 32 + quad * 8);
                acc[0][ns] = __builtin_amdgcn_mfma_f32_16x16x32_bf16(kfr, qf[0][kf], acc[0][ns], 0, 0, 0);
                acc[1][ns] = __builtin_amdgcn_mfma_f32_16x16x32_bf16(kfr, qf[1][kf], acc[1][ns], 0, 0, 0);
            }

        // ---- exp (no max-sub; |scores|<=~2) -> Es bf16, packed b64 writes
        if (c0 + CH_ <= ctx) {          // fast path: no masking needed
#pragma unroll
            for (int st = 0; st < 2; st++)
#pragma unroll
                for (int ns = 0; ns < 2; ns++) {
                    s16x4 wv;
#pragma unroll
                    for (int r = 0; r < 4; r++)
                        wv[r] = f2bs(__expf(acc[st][ns][r] * scale));
                    *(s16x4*)&U.s.Es[((wave + 4 * st) * 16 + l15) * ELD + ns * 16 + quad * 4] = wv;
                }
        } else {
#pragma unroll
            for (int st = 0; st < 2; st++)
#pragma unroll
                for (int ns = 0; ns < 2; ns++) {
                    s16x4 wv;
#pragma unroll
                    for (int r = 0; r < 4; r++) {
                        const int s = c0 + ns * 16 + quad * 4 + r;
                        float e = (s < ctx) ? __expf(acc[st][ns][r] * scale) : 0.f;
                        wv[r] = f2bs(e);
                    }
                    *(s16x4*)&U.s.Es[((wave + 4 * st) * 16 + l15) * ELD + ns * 16 + quad * 4] = wv;
                }
        }

        // ---- P@V via MFMA; V-frags shared across strips; tile 6 = denom
        short8 pf0 = ld_frag8(U.s.Es + (wave * 16 + l15) * ELD + quad * 8);
        short8 pf1 = ld_frag8(U.s.Es + ((wave + 4) * 16 + l15) * ELD + quad * 8);
#pragma unroll
        for (int nt = 0; nt < 7; nt++) {
            short8 vfr = *(const short8*)&U.s.Vt[(nt * 16 + l15) * VTLD + quad * 8];
            Oacc[0][nt] = __builtin_amdgcn_mfma_f32_16x16x32_bf16(pf0, vfr, Oacc[0][nt], 0, 0, 0);
            Oacc[1][nt] = __builtin_amdgcn_mfma_f32_16x16x32_bf16(pf1, vfr, Oacc[1][nt], 0, 0, 0);
        }
    }

    // ---- store partial O (bf16) + partial denominator (fp32)
    const size_t pb = (size_t)(slice * 512 + idx) * QR_;
#pragma unroll
    for (int st = 0; st < 2; st++)
#pragma unroll
        for (int r = 0; r < 4; r++) {
            const int row = (wave + 4 * st) * 16 + quad * 4 + r;
#pragma unroll
            for (int nt = 0; nt < 6; nt++)
                Opart[(pb + row) * DH_ + nt * 16 + l15] = __float2bfloat16(Oacc[st][nt][r]);
            if (l15 == 0) Dpart[pb + row] = Oacc[st][6][r];
        }
}

// ---------------------------------------------------------------------------
// combine: sum NS_ partials, normalize per token, masked mean-pool per line.
// ---------------------------------------------------------------------------
__global__ __launch_bounds__(256) void combine_pool(
    const bf16* __restrict__ Opart, const float* __restrict__ Dpart,
    const int* __restrict__ line_lens, bf16* __restrict__ opool)
{
    __shared__ float invd[LG_ * ML_];
    __shared__ int lens_s[LG_];
    const int idx = blockIdx.x;
    const int lg = idx & 15, bh = idx >> 4;
    const int h = bh & 7, b = bh >> 3;
    const int t = threadIdx.x;
    if (t < LG_) lens_s[t] = line_lens[b * L_ + lg * LG_ + t];
    if (t < LG_ * ML_) {
        float ds = 0.f;
#pragma unroll
        for (int s = 0; s < NS_; s++)
            ds += Dpart[(size_t)(s * 512 + idx) * QR_ + t];
        invd[t] = ds > 0.f ? 1.f / ds : 0.f;
    }
    __syncthreads();
    for (int q = t; q < LG_ * DH_; q += 256) {
        const int li = q / DH_, d = q - li * DH_;
        const int mm = min(lens_s[li], ML_);
        float acc = 0.f;
        for (int m = 0; m < mm; m++) {
            const int row = li * ML_ + m;
            float o = 0.f;
#pragma unroll
            for (int s = 0; s < NS_; s++)
                o += __bfloat162float(Opart[((size_t)(s * 512 + idx) * QR_ + row) * DH_ + d]);
            acc += o * invd[row];
        }
        const int line = lg * LG_ + li;
        opool[(size_t)(b * L_ + line) * H_ + h * DH_ + d] =
            __float2bfloat16(acc / (float)max(lens_s[li], 1));
    }
}

// ---------------------------------------------------------------------------
__global__ __launch_bounds__(256) void line_mean_k(
    const bf16* __restrict__ hidden, const int* __restrict__ line_starts,
    const int* __restrict__ line_lens, bf16* __restrict__ x)
{
    const int blk = blockIdx.x;
    const int b = blk >> 7, line = blk & 127;
    const int len = line_lens[b * L_ + line];
    const int start = line_starts[b * L_ + line];
    const int mm = min(len, ML_);
    const float inv = 1.f / (float)max(len, 1);
    for (int d = threadIdx.x; d < H_; d += 256) {
        float s = 0.f;
        for (int m = 0; m < mm; m++) {
            int sp = min(max(start + m, 0), S_ - 1);
            s += __bfloat162float(hidden[(size_t)(b * S_ + sp) * H_ + d]);
        }
        x[(size_t)blk * H2_ + d] = __float2bfloat16(s * inv);
    }
}

// ---------------------------------------------------------------------------
__global__ __launch_bounds__(256) void ln_gelu_k(
    const float* __restrict__ hin, const float* __restrict__ g,
    const float* __restrict__ be, float* __restrict__ uout, bf16* __restrict__ ubf)
{
    __shared__ float red[16];
    const int row = blockIdx.x, t = threadIdx.x;
    const float* hr = hin + (size_t)row * H_;
    float v[3];
    float s1 = 0.f, s2 = 0.f;
#pragma unroll
    for (int k = 0; k < 3; k++) {
        v[k] = hr[t + k * 256];
        s1 += v[k]; s2 += v[k] * v[k];
    }
#pragma unroll
    for (int m = 1; m < 64; m <<= 1) { s1 += __shfl_xor(s1, m, 64); s2 += __shfl_xor(s2, m, 64); }
    const int wave = t >> 6, lane = t & 63;
    if (lane == 0) { red[wave] = s1; red[8 + wave] = s2; }
    __syncthreads();
    s1 = red[0] + red[1] + red[2] + red[3];
    s2 = red[8] + red[9] + red[10] + red[11];
    const float mean = s1 * (1.f / H_);
    const float var = s2 * (1.f / H_) - mean * mean;
    const float rstd = 1.f / sqrtf(var + 1e-5f);
#pragma unroll
    for (int k = 0; k < 3; k++) {
        const int d = t + k * 256;
        float y = (v[k] - mean) * rstd * g[d] + be[d];
        y = gelu_exact(y);
        uout[(size_t)row * H_ + d] = y;
        ubf[(size_t)row * H_ + d] = __float2bfloat16(y);
    }
}

// ---------------------------------------------------------------------------
__global__ __launch_bounds__(256) void final_k(
    const float* __restrict__ h2, const float* __restrict__ u,
    const float* __restrict__ g2, const float* __restrict__ be2,
    const float* __restrict__ W3, const float* __restrict__ b3,
    const int* __restrict__ line_lens, float* __restrict__ out)
{
    __shared__ float red[16];
    const int row = blockIdx.x, t = threadIdx.x;
    const float* hr = h2 + (size_t)row * H_;
    float v[3];
    float s1 = 0.f, s2 = 0.f;
#pragma unroll
    for (int k = 0; k < 3; k++) {
        v[k] = hr[t + k * 256];
        s1 += v[k]; s2 += v[k] * v[k];
    }
#pragma unroll
    for (int m = 1; m < 64; m <<= 1) { s1 += __shfl_xor(s1, m, 64); s2 += __shfl_xor(s2, m, 64); }
    const int wave = t >> 6, lane = t & 63;
    if (lane == 0) { red[wave] = s1; red[8 + wave] = s2; }
    __syncthreads();
    s1 = red[0] + red[1] + red[2] + red[3];
    s2 = red[8] + red[9] + red[10] + red[11];
    const float mean = s1 * (1.f / H_);
    const float var = s2 * (1.f / H_) - mean * mean;
    const float rstd = 1.f / sqrtf(var + 1e-5f);
    float dotp = 0.f;
#pragma unroll
    for (int k = 0; k < 3; k++) {
        const int d = t + k * 256;
        float y = (v[k] - mean) * rstd * g2[d] + be2[d];
        y = u[(size_t)row * H_ + d] + gelu_exact(y);
        dotp += y * W3[d];
    }
#pragma unroll
    for (int m = 1; m < 64; m <<= 1) dotp += __shfl_xor(dotp, m, 64);
    __syncthreads();
    if (lane == 0) red[wave] = dotp;
    __syncthreads();
    if (t == 0) {
        float logit = red[0] + red[1] + red[2] + red[3] + b3[0];
        if (line_lens[row] <= 0) logit = -10.f;
        out[row] = 1.f / (1.f + __expf(-logit));
    }
}

// ---------------------------------------------------------------------------
extern "C" void kernel_launch(void* const* d_in, const int* in_sizes, int n_in,
                              void* d_out, int out_size, void* d_ws, size_t ws_size,
                              hipStream_t stream)
{
    const float* hidden     = (const float*)d_in[0];
    const float* in_proj_w  = (const float*)d_in[1];
    const float* in_proj_b  = (const float*)d_in[2];
    const float* out_proj_w = (const float*)d_in[3];
    const float* out_proj_b = (const float*)d_in[4];
    const float* W1         = (const float*)d_in[5];
    const float* b1         = (const float*)d_in[6];
    const float* g1         = (const float*)d_in[7];
    const float* be1        = (const float*)d_in[8];
    const float* W2         = (const float*)d_in[9];
    const float* b2         = (const float*)d_in[10];
    const float* g2         = (const float*)d_in[11];
    const float* be2        = (const float*)d_in[12];
    const float* W3         = (const float*)d_in[13];
    const float* b3         = (const float*)d_in[14];
    const int* line_starts  = (const int*)d_in[15];
    const int* line_lens    = (const int*)d_in[16];
    const int* context_len  = (const int*)d_in[17];

    const int BL = B_ * L_;                       // 512
    const size_t nh = (size_t)B_ * S_ * H_;       // 6291456
    const size_t nw = (size_t)H3_ * H_;           // 1769472
    const size_t opart_n = (size_t)NS_ * 512 * QR_ * DH_;  // 12.58M bf16

    char* w = (char*)d_ws;
    bf16* qk    = (bf16*)w;  w += (size_t)B_ * S_ * H2_ * sizeof(bf16);   // 25.17 MB
    bf16* vtg   = (bf16*)w;  w += (size_t)B_ * NH_ * DH_ * S_ * sizeof(bf16); // 12.58 MB
    char* ovl = w;
    bf16* hb    = (bf16*)ovl;                         // 12.58 MB
    bf16* wqkvb = (bf16*)(ovl + nh * sizeof(bf16));   //  3.54 MB
    bf16* Opart = (bf16*)ovl;                         // 25.17 MB (aliases hb/wqkvb AFTER they die)
    w = ovl + opart_n * sizeof(bf16);
    float* Dpart = (float*)w; w += (size_t)NS_ * 512 * QR_ * sizeof(float);
    bf16* opool = (bf16*)w;  w += (size_t)BL * H_ * sizeof(bf16);
    bf16* x     = (bf16*)w;  w += (size_t)BL * H2_ * sizeof(bf16);
    float* h1   = (float*)w; w += (size_t)BL * H_ * sizeof(float);
    float* uu   = (float*)w; w += (size_t)BL * H_ * sizeof(float);
    bf16* ubf   = (bf16*)w;  w += (size_t)BL * H_ * sizeof(bf16);
    float* h2   = (float*)w; w += (size_t)BL * H_ * sizeof(float);

    // bf16 copies of the two big GEMM-1 operands (single launch)
    f2b2_k<<<(int)((nh + nw) / (256 * 8)), 256, 0, stream>>>(
        hidden, hb, (int)nh, in_proj_w, wqkvb, (int)nw);

    // qkv projection: Q/K -> qk row-major, V -> vtg transposed [b,h,d,s]
    gemm128_qkv<<<dim3(B_ * S_ / 128, H3_ / 128), 256, 0, stream>>>(
        hb, wqkvb, in_proj_b, qk, vtg, B_ * S_, H_);
    // x[:, :H] = line_mean  (reads hb — MUST precede attn_slice, which overwrites it)
    line_mean_k<<<BL, 256, 0, stream>>>(hb, line_starts, line_lens, x);
    // attention partials over NS_ S-slices
    attn_slice<<<dim3(512, NS_), 256, 0, stream>>>(
        qk, vtg, line_starts, line_lens, context_len, Opart, Dpart);
    // normalize + masked mean-pool (pool commutes with out_proj)
    combine_pool<<<512, 256, 0, stream>>>(Opart, Dpart, line_lens, opool);
    // x[:, H:2H] = opool @ out_proj_w^T + out_proj_b
    gemm_bt<bf16, float, true><<<dim3(BL / 64, H_ / 64), 256, 0, stream>>>(
        opool, out_proj_w, out_proj_b, x, BL, H_, H_, H2_, H_);
    // h1 = x @ W1^T + b1 (fp32 out)
    gemm_bt<bf16, float, false><<<dim3(BL / 64, H_ / 64), 256, 0, stream>>>(
        x, W1, b1, h1, BL, H_, H2_, H_, 0);
    // u = gelu(LN(h1))
    ln_gelu_k<<<BL, 256, 0, stream>>>(h1, g1, be1, uu, ubf);
    // h2 = u @ W2^T + b2 (fp32 out)
    gemm_bt<bf16, float, false><<<dim3(BL / 64, H_ / 64), 256, 0, stream>>>(
        ubf, W2, b2, h2, BL, H_, H_, H_, 0);
    // out = sigmoid((u + gelu(LN(h2))) @ W3^T + b3)
    final_k<<<BL, 256, 0, stream>>>(h2, uu, g2, be2, W3, b3, line_lens, (float*)d_out);
}

// Round 11
// 319.595 us; speedup vs baseline: 1.3787x; 1.3787x over previous
//
#include <hip/hip_runtime.h>
#include <hip/hip_bf16.h>
#include <cmath>

using bf16 = __hip_bfloat16;
typedef __attribute__((ext_vector_type(8))) short short8;
typedef __attribute__((ext_vector_type(4))) short s16x4;
typedef __attribute__((ext_vector_type(4))) float f32x4;

#define B_   4
#define S_   2048
#define H_   768
#define H2_  1536
#define H3_  2304
#define NH_  8
#define DH_  96
#define L_   128
#define ML_  15
#define LG_  8
#define QR_  128
#define CH_  32
#define NS_  2       // NS_=4 measured WORSE (R8)
#define SLC_ (S_ / NS_)
#define ELD  36      // Es row stride (shorts): 18dw, clean
#define VTLD 40      // Vt row stride: 20dw, 2-way free
#define KLD  104     // Ks/Qs row stride: 52dw, 2-way free
#define VTR  112     // 96 d + 16 ones-rows (denominator trick)
#define ALD  40      // gemm tile stride: 20dw (32 was 8..16-way)
// NOTE: BK=64 variant (R10) spilled prefetch regs -> 400MB scratch writes. Keep BK=32.

__device__ __forceinline__ float gelu_exact(float v) {
    return 0.5f * v * (1.0f + erff(v * 0.7071067811865475f));
}
__device__ __forceinline__ short f2bs(float f) {
    bf16 h = __float2bfloat16(f);
    return *reinterpret_cast<short*>(&h);
}
__device__ __forceinline__ short8 ld_frag8(const short* p) {
    union { short8 v; s16x4 h[2]; } u;
    u.h[0] = *(const s16x4*)p;
    u.h[1] = *(const s16x4*)(p + 4);
    return u.v;
}

// fp32 -> bf16 bulk convert of hidden (n1) and in_proj_w (n2), one launch
__global__ __launch_bounds__(256) void f2b2_k(
    const float* __restrict__ s1, bf16* __restrict__ d1, int n1,
    const float* __restrict__ s2, bf16* __restrict__ d2, int n2)
{
    const int i = (blockIdx.x * 256 + threadIdx.x) * 8;
    const float* src; bf16* dst; int off;
    if (i < n1) { src = s1; dst = d1; off = i; }
    else if (i < n1 + n2) { src = s2; dst = d2; off = i - n1; }
    else return;
    float4 a = *(const float4*)(src + off);
    float4 b = *(const float4*)(src + off + 4);
    short8 r;
    r[0] = f2bs(a.x); r[1] = f2bs(a.y); r[2] = f2bs(a.z); r[3] = f2bs(a.w);
    r[4] = f2bs(b.x); r[5] = f2bs(b.y); r[6] = f2bs(b.z); r[7] = f2bs(b.w);
    *(short8*)(dst + off) = r;
}

// register pack for 8 elements of bf16/fp32 (prefetch staging)
template <typename T> struct Pk8;
template <> struct Pk8<bf16>  { int4 v; };
template <> struct Pk8<float> { float4 a, b; };
template <typename T> __device__ __forceinline__ Pk8<T> ld8(const T* p);
template <> __device__ __forceinline__ Pk8<bf16> ld8(const bf16* p) {
    Pk8<bf16> r; r.v = *(const int4*)p; return r;
}
template <> __device__ __forceinline__ Pk8<float> ld8(const float* p) {
    Pk8<float> r; r.a = *(const float4*)p; r.b = *(const float4*)(p + 4); return r;
}
template <typename T> __device__ __forceinline__ void st8(const Pk8<T>& v, bf16* dst);
template <> __device__ __forceinline__ void st8<bf16>(const Pk8<bf16>& v, bf16* dst) {
    *(int4*)dst = v.v;
}
template <> __device__ __forceinline__ void st8<float>(const Pk8<float>& v, bf16* dst) {
    short8 r;
    r[0] = f2bs(v.a.x); r[1] = f2bs(v.a.y); r[2] = f2bs(v.a.z); r[3] = f2bs(v.a.w);
    r[4] = f2bs(v.b.x); r[5] = f2bs(v.b.y); r[6] = f2bs(v.b.z); r[7] = f2bs(v.b.w);
    *(short8*)dst = r;
}

// ---------------------------------------------------------------------------
// 128x128-tile qkv GEMM (R9-proven): BK=32, register prefetch (4x int4),
// LDS stride ALD=40. Q/K cols -> qk row-major; V cols -> vt transposed.
// ---------------------------------------------------------------------------
__global__ __launch_bounds__(256) void gemm128_qkv(
    const bf16* __restrict__ A, const bf16* __restrict__ Bm,
    const float* __restrict__ bias, bf16* __restrict__ qk,
    bf16* __restrict__ vt, int M, int K)
{
    __shared__ alignas(16) bf16 As[128 * ALD];
    __shared__ alignas(16) bf16 Bs[128 * ALD];
    const int t = threadIdx.x;
    const int wave = t >> 6, lane = t & 63;
    const int l15 = lane & 15, quad = lane >> 4;
    const int m0 = blockIdx.x * 128, n0 = blockIdx.y * 128;
    const int wm = wave & 1, wn = wave >> 1;
    const int srow = t >> 1, scol = (t & 1) * 16;   // each thread: 32B of one row

    const bf16* aP = A + (size_t)(m0 + srow) * K + scol;
    const bf16* bP = Bm + (size_t)(n0 + srow) * K + scol;
    bf16* aL = &As[srow * ALD + scol];
    bf16* bL = &Bs[srow * ALD + scol];

    f32x4 acc[4][4];
#pragma unroll
    for (int i = 0; i < 4; i++)
#pragma unroll
        for (int j = 0; j < 4; j++) acc[i][j] = (f32x4){0.f, 0.f, 0.f, 0.f};

    for (int k0 = 0; k0 < K; k0 += 32) {
        int4 ra0 = *(const int4*)(aP + k0);
        int4 ra1 = *(const int4*)(aP + k0 + 8);
        int4 rb0 = *(const int4*)(bP + k0);
        int4 rb1 = *(const int4*)(bP + k0 + 8);
        __syncthreads();
        *(int4*)aL = ra0; *(int4*)(aL + 8) = ra1;
        *(int4*)bL = rb0; *(int4*)(bL + 8) = rb1;
        __syncthreads();
        short8 af[4], bfq[4];
#pragma unroll
        for (int i = 0; i < 4; i++)
            af[i] = *(const short8*)&As[(wm * 64 + i * 16 + l15) * ALD + quad * 8];
#pragma unroll
        for (int j = 0; j < 4; j++)
            bfq[j] = *(const short8*)&Bs[(wn * 64 + j * 16 + l15) * ALD + quad * 8];
#pragma unroll
        for (int i = 0; i < 4; i++)
#pragma unroll
            for (int j = 0; j < 4; j++)
                acc[i][j] = __builtin_amdgcn_mfma_f32_16x16x32_bf16(af[i], bfq[j], acc[i][j], 0, 0, 0);
    }

    if (n0 < H2_) {
#pragma unroll
        for (int j = 0; j < 4; j++) {
            const int col = n0 + wn * 64 + j * 16 + l15;
            const float bv = bias[col];
#pragma unroll
            for (int i = 0; i < 4; i++) {
                const int row = m0 + wm * 64 + i * 16 + quad * 4;
#pragma unroll
                for (int r = 0; r < 4; r++)
                    qk[(size_t)(row + r) * H2_ + col] = __float2bfloat16(acc[i][j][r] + bv);
            }
        }
    } else {
#pragma unroll
        for (int j = 0; j < 4; j++) {
            const int col = n0 + wn * 64 + j * 16 + l15;
            const float bv = bias[col];
            const int dfull = col - H2_;
            const int hh = dfull / DH_, d = dfull - hh * DH_;
#pragma unroll
            for (int i = 0; i < 4; i++) {
                const int row = m0 + wm * 64 + i * 16 + quad * 4;
                const int b = row >> 11, s = row & (S_ - 1);
                s16x4 pk;
#pragma unroll
                for (int r = 0; r < 4; r++) pk[r] = f2bs(acc[i][j][r] + bv);
                *(s16x4*)&vt[((size_t)(b * NH_ + hh) * DH_ + d) * S_ + s] = pk;
            }
        }
    }
}

// ---------------------------------------------------------------------------
// 64x64-tile GEMM with register prefetch. LDS stride ALD=40.
// ---------------------------------------------------------------------------
template <typename TA, typename TB, bool OUT_BF16>
__global__ __launch_bounds__(256) void gemm_bt(
    const TA* __restrict__ A, const TB* __restrict__ Bm,
    const float* __restrict__ bias, void* __restrict__ Cout,
    int M, int N, int K, int ldc, int coff)
{
    __shared__ alignas(16) bf16 As[64 * ALD];
    __shared__ alignas(16) bf16 Bs[64 * ALD];
    const int t = threadIdx.x;
    const int wave = t >> 6, lane = t & 63;
    const int l15 = lane & 15, quad = lane >> 4;
    const int m0 = blockIdx.x * 64, n0 = blockIdx.y * 64;
    const int srow = t >> 2, schk = (t & 3) * 8;

    const TA* aPtr = A + (size_t)(m0 + srow) * K + schk;
    const TB* bPtr = Bm + (size_t)(n0 + srow) * K + schk;
    bf16* aL = &As[srow * ALD + schk];
    bf16* bL = &Bs[srow * ALD + schk];

    f32x4 acc[4] = {{0.f,0.f,0.f,0.f},{0.f,0.f,0.f,0.f},
                    {0.f,0.f,0.f,0.f},{0.f,0.f,0.f,0.f}};
    const int aoff = (wave * 16 + l15) * ALD + quad * 8;

    Pk8<TA> pa = ld8<TA>(aPtr);
    Pk8<TB> pb = ld8<TB>(bPtr);

    for (int k0 = 0; k0 < K; k0 += 32) {
        __syncthreads();
        st8<TA>(pa, aL);
        st8<TB>(pb, bL);
        __syncthreads();
        if (k0 + 32 < K) {
            pa = ld8<TA>(aPtr + k0 + 32);
            pb = ld8<TB>(bPtr + k0 + 32);
        }
        short8 af = *(const short8*)&As[aoff];
#pragma unroll
        for (int nt = 0; nt < 4; nt++) {
            short8 bfr = *(const short8*)&Bs[(nt * 16 + l15) * ALD + quad * 8];
            acc[nt] = __builtin_amdgcn_mfma_f32_16x16x32_bf16(af, bfr, acc[nt], 0, 0, 0);
        }
    }

#pragma unroll
    for (int nt = 0; nt < 4; nt++) {
        int col = n0 + nt * 16 + l15;
        float bv = bias[col];
#pragma unroll
        for (int r = 0; r < 4; r++) {
            int row = m0 + wave * 16 + quad * 4 + r;
            float v = acc[nt][r] + bv;
            if (OUT_BF16) ((bf16*)Cout)[(size_t)row * ldc + coff + col] = __float2bfloat16(v);
            else          ((float*)Cout)[(size_t)row * ldc + coff + col] = v;
        }
    }
}

// ---------------------------------------------------------------------------
// Attention slice (R7-proven core) + hoisted ones-rows + ctx-uniform exp
// fast path (R10 additions, small-register, kept).
// ---------------------------------------------------------------------------
__global__ __launch_bounds__(256) void attn_slice(
    const bf16* __restrict__ qk, const bf16* __restrict__ vtg,
    const int* __restrict__ line_starts, const int* __restrict__ line_lens,
    const int* __restrict__ context_len,
    bf16* __restrict__ Opart, float* __restrict__ Dpart)
{
    __shared__ alignas(16) union {
        short Qs[QR_ * KLD];                       // 26624 B (staging phase)
        struct {
            short Ks[CH_ * KLD];                   //  6656 B
            short Vt[VTR * VTLD];                  //  8960 B
            short Es[QR_ * ELD];                   //  9216 B
        } s;                                       // 24832 B
    } U;

    const int t = threadIdx.x;
    const int idx = blockIdx.x;          // (b*8+h)*16 + lg
    const int slice = blockIdx.y;
    const int lg = idx & 15;
    const int bh = idx >> 4;
    const int h = bh & 7, b = bh >> 3;
    const int ctx = context_len[b];
    const int wave = t >> 6, lane = t & 63;
    const int l15 = lane & 15, quad = lane >> 4;

    // ---- stage Q: 128 rows x 96 bf16 (pad/invalid rows -> 0), stride KLD
    for (int ii = t; ii < QR_ * 12; ii += 256) {
        const int r = ii / 12, ck = ii - r * 12;
        int4 val; val.x = val.y = val.z = val.w = 0;
        if (r < LG_ * ML_) {
            const int li = r / ML_, m = r - li * ML_;
            const int line = lg * LG_ + li;
            const int len = line_lens[b * L_ + line];
            if (m < len) {
                int sPos = line_starts[b * L_ + line] + m;
                sPos = min(max(sPos, 0), S_ - 1);
                val = *(const int4*)(qk + (size_t)(b * S_ + sPos) * H2_ + h * DH_ + ck * 8);
            }
        }
        *(int4*)&U.Qs[r * KLD + ck * 8] = val;
    }
    __syncthreads();

    short8 qf[2][3];
#pragma unroll
    for (int st = 0; st < 2; st++)
#pragma unroll
        for (int kf = 0; kf < 3; kf++)
            qf[st][kf] = *(const short8*)(U.Qs + ((wave + 4 * st) * 16 + l15) * KLD + kf * 32 + quad * 8);
    __syncthreads();   // Qs fully consumed -> union area reusable

    f32x4 Oacc[2][7];
#pragma unroll
    for (int st = 0; st < 2; st++)
#pragma unroll
        for (int nt = 0; nt < 7; nt++) Oacc[st][nt] = (f32x4){0.f, 0.f, 0.f, 0.f};

    const float scale = 0.10206207261596577f;  // 1/sqrt(96)
    const size_t kbase = (size_t)b * S_ * H2_ + H_ + h * DH_;
    const size_t vbase = (size_t)(b * NH_ + h) * DH_ * S_;
    const int cbase = slice * SLC_;

    const int k0r = t / 12,        k0c = t - k0r * 12;
    const int k1r = (256 + t) / 12, k1c = (256 + t) - k1r * 12;
    const int v0d = t >> 2,        v0s = (t & 3) * 8;
    const int v1d = (256 + t) >> 2, v1s = ((256 + t) & 3) * 8;
    const int on_r = t >> 4, on_c = t & 15;

    int4 rk0, rk1, rv0, rv1;
    {
        rk0 = *(const int4*)(qk + kbase + (size_t)(cbase + k0r) * H2_ + k0c * 8);
        rv0 = *(const int4*)(vtg + vbase + (size_t)v0d * S_ + cbase + v0s);
        if (t < 128) {
            rk1 = *(const int4*)(qk + kbase + (size_t)(cbase + k1r) * H2_ + k1c * 8);
            rv1 = *(const int4*)(vtg + vbase + (size_t)v1d * S_ + cbase + v1s);
        }
    }

    int ones_state = -1;   // -1 unwritten, 0 all-zero, 1 all-one, 2 mixed

    for (int ci = 0; ci < SLC_ / CH_; ci++) {
        const int c0 = cbase + ci * CH_;
        __syncthreads();
        *(int4*)&U.s.Ks[k0r * KLD + k0c * 8] = rk0;
        *(int4*)&U.s.Vt[v0d * VTLD + v0s] = rv0;
        if (t < 128) {
            *(int4*)&U.s.Ks[k1r * KLD + k1c * 8] = rk1;
            *(int4*)&U.s.Vt[v1d * VTLD + v1s] = rv1;
        }
        {   // ones-rows 96..111: rewrite only when mask pattern changes
            const int st_now = (c0 + CH_ <= ctx) ? 1 : ((c0 >= ctx) ? 0 : 2);
            if (st_now != ones_state || st_now == 2) {
                unsigned int lo = (c0 + 2 * on_c)     < ctx ? 0x3f80u : 0u;
                unsigned int hi = (c0 + 2 * on_c + 1) < ctx ? 0x3f80u : 0u;
                ((unsigned int*)&U.s.Vt[(96 + on_r) * VTLD])[on_c] = lo | (hi << 16);
                ones_state = st_now;
            }
        }
        __syncthreads();

        if (ci + 1 < SLC_ / CH_) {
            const int cn = c0 + CH_;
            rk0 = *(const int4*)(qk + kbase + (size_t)(cn + k0r) * H2_ + k0c * 8);
            rv0 = *(const int4*)(vtg + vbase + (size_t)v0d * S_ + cn + v0s);
            if (t < 128) {
                rk1 = *(const int4*)(qk + kbase + (size_t)(cn + k1r) * H2_ + k1c * 8);
                rv1 = *(const int4*)(vtg + vbase + (size_t)v1d * S_ + cn + v1s);
            }
        }

        // ---- S^T = K*Q^T via MFMA (A=K rows s, B=Q cols q)
        f32x4 acc[2][2] = {{{0.f,0.f,0.f,0.f},{0.f,0.f,0.f,0.f}},
                           {{0.f,0.f,0.f,0.f},{0.f,0.f,0.f,0.f}}};
#pragma unroll
        for (int ns = 0; ns < 2; ns++)
#pragma unroll
            for (int kf = 0; kf < 3; kf++) {
                short8 kfr = *(const short8*)(U.s.Ks + (ns * 16 + l15) * KLD + kf * 32 + quad * 8);
                acc[0][ns] = __builtin_amdgcn_mfma_f32_16x16x32_bf16(kfr, qf[0][kf], acc[0][ns], 0, 0, 0);
                acc[1][ns] = __builtin_amdgcn_mfma_f32_16x16x32_bf16(kfr, qf[1][kf], acc[1][ns], 0, 0, 0);
            }

        // ---- exp (no max-sub; |scores|<=~2) -> Es bf16, packed b64 writes
        if (c0 + CH_ <= ctx) {          // fast path: no masking needed
#pragma unroll
            for (int st = 0; st < 2; st++)
#pragma unroll
                for (int ns = 0; ns < 2; ns++) {
                    s16x4 wv;
#pragma unroll
                    for (int r = 0; r < 4; r++)
                        wv[r] = f2bs(__expf(acc[st][ns][r] * scale));
                    *(s16x4*)&U.s.Es[((wave + 4 * st) * 16 + l15) * ELD + ns * 16 + quad * 4] = wv;
                }
        } else {
#pragma unroll
            for (int st = 0; st < 2; st++)
#pragma unroll
                for (int ns = 0; ns < 2; ns++) {
                    s16x4 wv;
#pragma unroll
                    for (int r = 0; r < 4; r++) {
                        const int s = c0 + ns * 16 + quad * 4 + r;
                        float e = (s < ctx) ? __expf(acc[st][ns][r] * scale) : 0.f;
                        wv[r] = f2bs(e);
                    }
                    *(s16x4*)&U.s.Es[((wave + 4 * st) * 16 + l15) * ELD + ns * 16 + quad * 4] = wv;
                }
        }

        // ---- P@V via MFMA; V-frags shared across strips; tile 6 = denom
        short8 pf0 = ld_frag8(U.s.Es + (wave * 16 + l15) * ELD + quad * 8);
        short8 pf1 = ld_frag8(U.s.Es + ((wave + 4) * 16 + l15) * ELD + quad * 8);
#pragma unroll
        for (int nt = 0; nt < 7; nt++) {
            short8 vfr = *(const short8*)&U.s.Vt[(nt * 16 + l15) * VTLD + quad * 8];
            Oacc[0][nt] = __builtin_amdgcn_mfma_f32_16x16x32_bf16(pf0, vfr, Oacc[0][nt], 0, 0, 0);
            Oacc[1][nt] = __builtin_amdgcn_mfma_f32_16x16x32_bf16(pf1, vfr, Oacc[1][nt], 0, 0, 0);
        }
    }

    // ---- store partial O (bf16) + partial denominator (fp32)
    const size_t pb = (size_t)(slice * 512 + idx) * QR_;
#pragma unroll
    for (int st = 0; st < 2; st++)
#pragma unroll
        for (int r = 0; r < 4; r++) {
            const int row = (wave + 4 * st) * 16 + quad * 4 + r;
#pragma unroll
            for (int nt = 0; nt < 6; nt++)
                Opart[(pb + row) * DH_ + nt * 16 + l15] = __float2bfloat16(Oacc[st][nt][r]);
            if (l15 == 0) Dpart[pb + row] = Oacc[st][6][r];
        }
}

// ---------------------------------------------------------------------------
// combine: sum NS_ partials, normalize per token, masked mean-pool per line.
// ---------------------------------------------------------------------------
__global__ __launch_bounds__(256) void combine_pool(
    const bf16* __restrict__ Opart, const float* __restrict__ Dpart,
    const int* __restrict__ line_lens, bf16* __restrict__ opool)
{
    __shared__ float invd[LG_ * ML_];
    __shared__ int lens_s[LG_];
    const int idx = blockIdx.x;
    const int lg = idx & 15, bh = idx >> 4;
    const int h = bh & 7, b = bh >> 3;
    const int t = threadIdx.x;
    if (t < LG_) lens_s[t] = line_lens[b * L_ + lg * LG_ + t];
    if (t < LG_ * ML_) {
        float ds = 0.f;
#pragma unroll
        for (int s = 0; s < NS_; s++)
            ds += Dpart[(size_t)(s * 512 + idx) * QR_ + t];
        invd[t] = ds > 0.f ? 1.f / ds : 0.f;
    }
    __syncthreads();
    for (int q = t; q < LG_ * DH_; q += 256) {
        const int li = q / DH_, d = q - li * DH_;
        const int mm = min(lens_s[li], ML_);
        float acc = 0.f;
        for (int m = 0; m < mm; m++) {
            const int row = li * ML_ + m;
            float o = 0.f;
#pragma unroll
            for (int s = 0; s < NS_; s++)
                o += __bfloat162float(Opart[((size_t)(s * 512 + idx) * QR_ + row) * DH_ + d]);
            acc += o * invd[row];
        }
        const int line = lg * LG_ + li;
        opool[(size_t)(b * L_ + line) * H_ + h * DH_ + d] =
            __float2bfloat16(acc / (float)max(lens_s[li], 1));
    }
}

// ---------------------------------------------------------------------------
__global__ __launch_bounds__(256) void line_mean_k(
    const bf16* __restrict__ hidden, const int* __restrict__ line_starts,
    const int* __restrict__ line_lens, bf16* __restrict__ x)
{
    const int blk = blockIdx.x;
    const int b = blk >> 7, line = blk & 127;
    const int len = line_lens[b * L_ + line];
    const int start = line_starts[b * L_ + line];
    const int mm = min(len, ML_);
    const float inv = 1.f / (float)max(len, 1);
    for (int d = threadIdx.x; d < H_; d += 256) {
        float s = 0.f;
        for (int m = 0; m < mm; m++) {
            int sp = min(max(start + m, 0), S_ - 1);
            s += __bfloat162float(hidden[(size_t)(b * S_ + sp) * H_ + d]);
        }
        x[(size_t)blk * H2_ + d] = __float2bfloat16(s * inv);
    }
}

// ---------------------------------------------------------------------------
__global__ __launch_bounds__(256) void ln_gelu_k(
    const float* __restrict__ hin, const float* __restrict__ g,
    const float* __restrict__ be, float* __restrict__ uout, bf16* __restrict__ ubf)
{
    __shared__ float red[16];
    const int row = blockIdx.x, t = threadIdx.x;
    const float* hr = hin + (size_t)row * H_;
    float v[3];
    float s1 = 0.f, s2 = 0.f;
#pragma unroll
    for (int k = 0; k < 3; k++) {
        v[k] = hr[t + k * 256];
        s1 += v[k]; s2 += v[k] * v[k];
    }
#pragma unroll
    for (int m = 1; m < 64; m <<= 1) { s1 += __shfl_xor(s1, m, 64); s2 += __shfl_xor(s2, m, 64); }
    const int wave = t >> 6, lane = t & 63;
    if (lane == 0) { red[wave] = s1; red[8 + wave] = s2; }
    __syncthreads();
    s1 = red[0] + red[1] + red[2] + red[3];
    s2 = red[8] + red[9] + red[10] + red[11];
    const float mean = s1 * (1.f / H_);
    const float var = s2 * (1.f / H_) - mean * mean;
    const float rstd = 1.f / sqrtf(var + 1e-5f);
#pragma unroll
    for (int k = 0; k < 3; k++) {
        const int d = t + k * 256;
        float y = (v[k] - mean) * rstd * g[d] + be[d];
        y = gelu_exact(y);
        uout[(size_t)row * H_ + d] = y;
        ubf[(size_t)row * H_ + d] = __float2bfloat16(y);
    }
}

// ---------------------------------------------------------------------------
__global__ __launch_bounds__(256) void final_k(
    const float* __restrict__ h2, const float* __restrict__ u,
    const float* __restrict__ g2, const float* __restrict__ be2,
    const float* __restrict__ W3, const float* __restrict__ b3,
    const int* __restrict__ line_lens, float* __restrict__ out)
{
    __shared__ float red[16];
    const int row = blockIdx.x, t = threadIdx.x;
    const float* hr = h2 + (size_t)row * H_;
    float v[3];
    float s1 = 0.f, s2 = 0.f;
#pragma unroll
    for (int k = 0; k < 3; k++) {
        v[k] = hr[t + k * 256];
        s1 += v[k]; s2 += v[k] * v[k];
    }
#pragma unroll
    for (int m = 1; m < 64; m <<= 1) { s1 += __shfl_xor(s1, m, 64); s2 += __shfl_xor(s2, m, 64); }
    const int wave = t >> 6, lane = t & 63;
    if (lane == 0) { red[wave] = s1; red[8 + wave] = s2; }
    __syncthreads();
    s1 = red[0] + red[1] + red[2] + red[3];
    s2 = red[8] + red[9] + red[10] + red[11];
    const float mean = s1 * (1.f / H_);
    const float var = s2 * (1.f / H_) - mean * mean;
    const float rstd = 1.f / sqrtf(var + 1e-5f);
    float dotp = 0.f;
#pragma unroll
    for (int k = 0; k < 3; k++) {
        const int d = t + k * 256;
        float y = (v[k] - mean) * rstd * g2[d] + be2[d];
        y = u[(size_t)row * H_ + d] + gelu_exact(y);
        dotp += y * W3[d];
    }
#pragma unroll
    for (int m = 1; m < 64; m <<= 1) dotp += __shfl_xor(dotp, m, 64);
    __syncthreads();
    if (lane == 0) red[wave] = dotp;
    __syncthreads();
    if (t == 0) {
        float logit = red[0] + red[1] + red[2] + red[3] + b3[0];
        if (line_lens[row] <= 0) logit = -10.f;
        out[row] = 1.f / (1.f + __expf(-logit));
    }
}

// ---------------------------------------------------------------------------
extern "C" void kernel_launch(void* const* d_in, const int* in_sizes, int n_in,
                              void* d_out, int out_size, void* d_ws, size_t ws_size,
                              hipStream_t stream)
{
    const float* hidden     = (const float*)d_in[0];
    const float* in_proj_w  = (const float*)d_in[1];
    const float* in_proj_b  = (const float*)d_in[2];
    const float* out_proj_w = (const float*)d_in[3];
    const float* out_proj_b = (const float*)d_in[4];
    const float* W1         = (const float*)d_in[5];
    const float* b1         = (const float*)d_in[6];
    const float* g1         = (const float*)d_in[7];
    const float* be1        = (const float*)d_in[8];
    const float* W2         = (const float*)d_in[9];
    const float* b2         = (const float*)d_in[10];
    const float* g2         = (const float*)d_in[11];
    const float* be2        = (const float*)d_in[12];
    const float* W3         = (const float*)d_in[13];
    const float* b3         = (const float*)d_in[14];
    const int* line_starts  = (const int*)d_in[15];
    const int* line_lens    = (const int*)d_in[16];
    const int* context_len  = (const int*)d_in[17];

    const int BL = B_ * L_;                       // 512
    const size_t nh = (size_t)B_ * S_ * H_;       // 6291456
    const size_t nw = (size_t)H3_ * H_;           // 1769472
    const size_t opart_n = (size_t)NS_ * 512 * QR_ * DH_;  // 12.58M bf16

    char* w = (char*)d_ws;
    bf16* qk    = (bf16*)w;  w += (size_t)B_ * S_ * H2_ * sizeof(bf16);   // 25.17 MB
    bf16* vtg   = (bf16*)w;  w += (size_t)B_ * NH_ * DH_ * S_ * sizeof(bf16); // 12.58 MB
    char* ovl = w;
    bf16* hb    = (bf16*)ovl;                         // 12.58 MB
    bf16* wqkvb = (bf16*)(ovl + nh * sizeof(bf16));   //  3.54 MB
    bf16* Opart = (bf16*)ovl;                         // 25.17 MB (aliases hb/wqkvb AFTER they die)
    w = ovl + opart_n * sizeof(bf16);
    float* Dpart = (float*)w; w += (size_t)NS_ * 512 * QR_ * sizeof(float);
    bf16* opool = (bf16*)w;  w += (size_t)BL * H_ * sizeof(bf16);
    bf16* x     = (bf16*)w;  w += (size_t)BL * H2_ * sizeof(bf16);
    float* h1   = (float*)w; w += (size_t)BL * H_ * sizeof(float);
    float* uu   = (float*)w; w += (size_t)BL * H_ * sizeof(float);
    bf16* ubf   = (bf16*)w;  w += (size_t)BL * H_ * sizeof(bf16);
    float* h2   = (float*)w; w += (size_t)BL * H_ * sizeof(float);

    // bf16 copies of the two big GEMM-1 operands (single launch)
    f2b2_k<<<(int)((nh + nw) / (256 * 8)), 256, 0, stream>>>(
        hidden, hb, (int)nh, in_proj_w, wqkvb, (int)nw);

    // qkv projection: Q/K -> qk row-major, V -> vtg transposed [b,h,d,s]
    gemm128_qkv<<<dim3(B_ * S_ / 128, H3_ / 128), 256, 0, stream>>>(
        hb, wqkvb, in_proj_b, qk, vtg, B_ * S_, H_);
    // x[:, :H] = line_mean  (reads hb — MUST precede attn_slice, which overwrites it)
    line_mean_k<<<BL, 256, 0, stream>>>(hb, line_starts, line_lens, x);
    // attention partials over NS_ S-slices
    attn_slice<<<dim3(512, NS_), 256, 0, stream>>>(
        qk, vtg, line_starts, line_lens, context_len, Opart, Dpart);
    // normalize + masked mean-pool (pool commutes with out_proj)
    combine_pool<<<512, 256, 0, stream>>>(Opart, Dpart, line_lens, opool);
    // x[:, H:2H] = opool @ out_proj_w^T + out_proj_b
    gemm_bt<bf16, float, true><<<dim3(BL / 64, H_ / 64), 256, 0, stream>>>(
        opool, out_proj_w, out_proj_b, x, BL, H_, H_, H2_, H_);
    // h1 = x @ W1^T + b1 (fp32 out)
    gemm_bt<bf16, float, false><<<dim3(BL / 64, H_ / 64), 256, 0, stream>>>(
        x, W1, b1, h1, BL, H_, H2_, H_, 0);
    // u = gelu(LN(h1))
    ln_gelu_k<<<BL, 256, 0, stream>>>(h1, g1, be1, uu, ubf);
    // h2 = u @ W2^T + b2 (fp32 out)
    gemm_bt<bf16, float, false><<<dim3(BL / 64, H_ / 64), 256, 0, stream>>>(
        ubf, W2, b2, h2, BL, H_, H_, H_, 0);
    // out = sigmoid((u + gelu(LN(h2))) @ W3^T + b3)
    final_k<<<BL, 256, 0, stream>>>(h2, uu, g2, be2, W3, b3, line_lens, (float*)d_out);
}